// Round 9
// baseline (4268.015 us; speedup 1.0000x reference)
//
#include <hip/hip_runtime.h>
#include <cstddef>

// ---------------------------------------------------------------------------
// Compile-time generation of real-basis Clebsch-Gordan tensors (e3nn conv.)
// (verified correct in rounds 1-8)
// ---------------------------------------------------------------------------
namespace so3 {

constexpr int IRR  = 16;
constexpr int CIN  = 128;
constexpr int COUT = 128;
constexpr int NP   = 34;
constexpr int NNODES = 16384;
constexpr int MT   = 16;

constexpr int H_L1[NP] = {0,1,2,3, 0,1,1,1,2,2,2,3,3, 0,1,1,1,2,2,2,2,3,3,3, 0,1,1,2,2,2,3,3,3,3};
constexpr int H_L2[NP] = {0,1,2,3, 1,0,1,2,1,2,3,2,3, 2,1,2,3,0,1,2,3,1,2,3, 3,2,3,1,2,3,0,1,2,3};
constexpr int H_LO[NP] = {0,0,0,0, 1,1,1,1,1,1,1,1,1, 2,2,2,2,2,2,2,2,2,2,2, 3,3,3,3,3,3,3,3,3,3};
constexpr int H_START[4] = {0,4,13,24};
constexpr int H_CNT[4]   = {4,9,11,10};

constexpr double cfac(int n){ double r=1.0; for(int i=2;i<=n;++i) r *= (double)i; return r; }
constexpr double csqrt_(double x){
  if(x <= 0.0) return 0.0;
  double r = x < 1.0 ? 1.0 : x;
  for(int i=0;i<60;++i) r = 0.5*(r + x/r);
  return r;
}
constexpr double m1pow(int k){ return (k & 1) ? -1.0 : 1.0; }

struct CD { double re, im; };
constexpr CD cmul(CD a, CD b){ return CD{a.re*b.re - a.im*b.im, a.re*b.im + a.im*b.re}; }

struct CGDense { double v[7][7][7]; };
constexpr CGDense su2_cg(int j1,int j2,int j3){
  CGDense C{};
  for(int m1=-j1;m1<=j1;++m1){
    for(int m2=-j2;m2<=j2;++m2){
      int m3 = m1+m2;
      if(m3 < -j3 || m3 > j3) continue;
      double pref = csqrt_((2*j3+1) * cfac(j3+j1-j2)*cfac(j3-j1+j2)*cfac(j1+j2-j3)/cfac(j1+j2+j3+1));
      pref *= csqrt_(cfac(j3+m3)*cfac(j3-m3)*cfac(j1-m1)*cfac(j1+m1)*cfac(j2-m2)*cfac(j2+m2));
      double s = 0.0;
      for(int k=0;k<=j1+j2;++k){
        int d0=k, d1=j1+j2-j3-k, d2=j1-m1-k, d3=j2+m2-k, d4=j3-j2+m1+k, d5=j3-j1-m2+k;
        if(d0<0||d1<0||d2<0||d3<0||d4<0||d5<0) continue;
        s += m1pow(k)/(cfac(d0)*cfac(d1)*cfac(d2)*cfac(d3)*cfac(d4)*cfac(d5));
      }
      C.v[m1+j1][m2+j2][m3+j3] = pref*s;
    }
  }
  return C;
}

struct QMat { CD v[7][7]; };
constexpr QMat qmat(int l){
  QMat q{};
  const double r2 = 1.0/csqrt_(2.0);
  for(int m=-l;m<0;++m){
    q.v[l+m][l-m] = CD{r2, 0.0};
    q.v[l+m][l+m] = CD{0.0, -r2};
  }
  q.v[l][l] = CD{1.0, 0.0};
  for(int m=1;m<=l;++m){
    double sgn = m1pow(m);
    q.v[l+m][l+m] = CD{sgn*r2, 0.0};
    q.v[l+m][l-m] = CD{0.0, sgn*r2};
  }
  CD ph = CD{1.0, 0.0};
  int lm = l & 3;
  if(lm==1) ph = CD{0.0,-1.0};
  else if(lm==2) ph = CD{-1.0,0.0};
  else if(lm==3) ph = CD{0.0, 1.0};
  for(int i=0;i<2*l+1;++i)
    for(int j=0;j<2*l+1;++j)
      q.v[i][j] = cmul(q.v[i][j], ph);
  return q;
}

struct RealCG { double v[7][7][7]; };
constexpr RealCG real_cg(int l1,int l2,int l3){
  RealCG W{};
  const CGDense C = su2_cg(l1,l2,l3);
  const QMat q1 = qmat(l1), q2 = qmat(l2), q3 = qmat(l3);
  for(int i=0;i<2*l1+1;++i){
    int alist[2] = {i, 2*l1-i};
    int na = (alist[1]==alist[0]) ? 1 : 2;
    for(int j=0;j<2*l2+1;++j){
      int blist[2] = {j, 2*l2-j};
      int nb = (blist[1]==blist[0]) ? 1 : 2;
      for(int k=0;k<2*l3+1;++k){
        int clist[2] = {k, 2*l3-k};
        int nc = (clist[1]==clist[0]) ? 1 : 2;
        double re = 0.0;
        for(int ai=0;ai<na;++ai) for(int bi=0;bi<nb;++bi) for(int ci=0;ci<nc;++ci){
          int a=alist[ai], b=blist[bi], c=clist[ci];
          double cc = C.v[a][b][c];
          if(cc == 0.0) continue;
          CD t = cmul(cmul(q1.v[a][i], q2.v[b][j]), q3.v[c][k]);
          re += t.re * cc;
        }
        W.v[i][j][k] = re;
      }
    }
  }
  return W;
}

#define DECL_CG(n,a,b,c) constexpr RealCG CGP##n = real_cg(a,b,c);
DECL_CG(0,0,0,0)  DECL_CG(1,1,1,0)  DECL_CG(2,2,2,0)  DECL_CG(3,3,3,0)
DECL_CG(4,0,1,1)  DECL_CG(5,1,0,1)  DECL_CG(6,1,1,1)  DECL_CG(7,1,2,1)
DECL_CG(8,2,1,1)  DECL_CG(9,2,2,1)  DECL_CG(10,2,3,1) DECL_CG(11,3,2,1)
DECL_CG(12,3,3,1) DECL_CG(13,0,2,2) DECL_CG(14,1,1,2) DECL_CG(15,1,2,2)
DECL_CG(16,1,3,2) DECL_CG(17,2,0,2) DECL_CG(18,2,1,2) DECL_CG(19,2,2,2)
DECL_CG(20,2,3,2) DECL_CG(21,3,1,2) DECL_CG(22,3,2,2) DECL_CG(23,3,3,2)
DECL_CG(24,0,3,3) DECL_CG(25,1,2,3) DECL_CG(26,1,3,3) DECL_CG(27,2,1,3)
DECL_CG(28,2,2,3) DECL_CG(29,2,3,3) DECL_CG(30,3,0,3) DECL_CG(31,3,1,3)
DECL_CG(32,3,2,3) DECL_CG(33,3,3,3)
#undef DECL_CG

struct CGTable { float v[NP][7][7][7]; };
constexpr CGTable pack_cg(){
  const RealCG arr[NP] = {CGP0,CGP1,CGP2,CGP3,CGP4,CGP5,CGP6,CGP7,CGP8,CGP9,
                          CGP10,CGP11,CGP12,CGP13,CGP14,CGP15,CGP16,CGP17,CGP18,CGP19,
                          CGP20,CGP21,CGP22,CGP23,CGP24,CGP25,CGP26,CGP27,CGP28,CGP29,
                          CGP30,CGP31,CGP32,CGP33};
  CGTable t{};
  for(int p=0;p<NP;++p)
    for(int i=0;i<7;++i) for(int j=0;j<7;++j) for(int k=0;k<7;++k)
      t.v[p][i][j][k] = (float)arr[p].v[i][j][k];
  return t;
}

constexpr float PATH_SC[4] = {
  (float)(1.0/csqrt_((double)H_CNT[0])), (float)(1.0/csqrt_((double)H_CNT[1])),
  (float)(1.0/csqrt_((double)H_CNT[2])), (float)(1.0/csqrt_((double)H_CNT[3]))
};

// q-th path of the pair-kernel (LOA group then LOB group, canonical order)
constexpr int pid_of(int A, int B, int q){
  return q < H_CNT[A] ? H_START[A] + q : H_START[B] + (q - H_CNT[A]);
}

} // namespace so3

__constant__ so3::CGTable c_cg = so3::pack_cg();

typedef __attribute__((ext_vector_type(8))) short bhalf8;
typedef __attribute__((ext_vector_type(4))) float floatx4;

__device__ __forceinline__ unsigned f2bf(float f){
  unsigned u = __builtin_bit_cast(unsigned, f);
  return (u + 0x7fffu + ((u>>16)&1u)) >> 16;
}

// Raw barrier: LDS-count + s_barrier, NO vmcnt drain -> global loads stay in
// flight across intervals. All cross-thread traffic is LDS-only.
#define SO3_BAR() do{ __builtin_amdgcn_sched_barrier(0); \
  asm volatile("s_waitcnt lgkmcnt(0)" ::: "memory"); \
  __builtin_amdgcn_s_barrier(); \
  asm volatile("" ::: "memory"); \
  __builtin_amdgcn_sched_barrier(0); }while(0)

// ---------------------------------------------------------------------------
// Stage A (verified r1-r8): g[c][n][a] = sc * sum_b CG[a][b][c] * x2[n,l2^2+b]
// ---------------------------------------------------------------------------
template<int P>
__device__ __forceinline__ void stage_a(const int tid, float* __restrict__ gout,
                                        const float* __restrict__ x2s)
{
  using namespace so3;
  constexpr int lo = H_LO[P];
  constexpr int NR = 2*lo + 1;
  constexpr int l1 = H_L1[P], l2 = H_L2[P];
  constexpr int n1 = 2*l1 + 1, n2 = 2*l2 + 1;
  constexpr int GT = NR*16*8;
  #pragma unroll
  for (int e0 = 0; e0 < GT; e0 += 512) {
    const int e = e0 + tid;
    if (e < GT) {
      const int a = e & 7, n = (e >> 3) & 15, c = e >> 7;
      if (a < n1) {
        float s = 0.f;
        #pragma unroll
        for (int b = 0; b < n2; ++b)
          s += c_cg.v[P][a][b][c] * x2s[n*16 + l2*l2 + b];
        gout[e] = s * PATH_SC[lo];
      }
    }
  }
}

// ---------------------------------------------------------------------------
// One a-chunk of path P: z_j = x1_row(l1^2+A0+j) x W_p (MFMA, j<CS<=4), then
// acc[AOFF+c] += g[c][node][A0+j] * z_j. Named z0..z3 keep live set <=16 regs
// (rule #20: all indices compile-time). g reads are 16-lane broadcasts;
// chunk starts A0 in {0,4} keep float4 reads 16B-aligned in the stride-8 row.
// ---------------------------------------------------------------------------
template<int P, int AOFF, int A0, int CS>
__device__ __forceinline__ void chunk_op(const unsigned short* __restrict__ x1s,
    const float* __restrict__ gin, const bhalf8 (&bfrag)[4],
    floatx4 (&acc)[8], const int lr, const int lg, const unsigned xsw)
{
  using namespace so3;
  constexpr int l1 = H_L1[P];
  constexpr int NR = 2*H_LO[P] + 1;

  floatx4 z0 = {0.f,0.f,0.f,0.f}, z1 = {0.f,0.f,0.f,0.f};
  floatx4 z2 = {0.f,0.f,0.f,0.f}, z3 = {0.f,0.f,0.f,0.f};
  #pragma unroll
  for (int ks = 0; ks < 4; ++ks) {
    {
      const unsigned byte = ((unsigned)((((l1*l1 + A0 + 0)*16 + lr)*256) + ks*64 + lg*16)) ^ xsw;
      bhalf8 av = *(const bhalf8*)((const char*)x1s + byte);
      z0 = __builtin_amdgcn_mfma_f32_16x16x32_bf16(av, bfrag[ks], z0, 0, 0, 0);
    }
    if constexpr (CS > 1) {
      const unsigned byte = ((unsigned)((((l1*l1 + A0 + 1)*16 + lr)*256) + ks*64 + lg*16)) ^ xsw;
      bhalf8 av = *(const bhalf8*)((const char*)x1s + byte);
      z1 = __builtin_amdgcn_mfma_f32_16x16x32_bf16(av, bfrag[ks], z1, 0, 0, 0);
    }
    if constexpr (CS > 2) {
      const unsigned byte = ((unsigned)((((l1*l1 + A0 + 2)*16 + lr)*256) + ks*64 + lg*16)) ^ xsw;
      bhalf8 av = *(const bhalf8*)((const char*)x1s + byte);
      z2 = __builtin_amdgcn_mfma_f32_16x16x32_bf16(av, bfrag[ks], z2, 0, 0, 0);
    }
    if constexpr (CS > 3) {
      const unsigned byte = ((unsigned)((((l1*l1 + A0 + 3)*16 + lr)*256) + ks*64 + lg*16)) ^ xsw;
      bhalf8 av = *(const bhalf8*)((const char*)x1s + byte);
      z3 = __builtin_amdgcn_mfma_f32_16x16x32_bf16(av, bfrag[ks], z3, 0, 0, 0);
    }
  }

  #pragma unroll
  for (int c = 0; c < NR; ++c) {
    #pragma unroll
    for (int r = 0; r < 4; ++r) {
      const float* gp = gin + (c*16 + lg*4 + r)*8 + A0;
      if constexpr (CS == 1) {
        acc[AOFF + c][r] += gp[0] * z0[r];
      } else {
        const float4 g4 = *(const float4*)(gp);
        float s = g4.x * z0[r];
        if constexpr (CS > 1) s += g4.y * z1[r];
        if constexpr (CS > 2) s += g4.z * z2[r];
        if constexpr (CS > 3) s += g4.w * z3[r];
        acc[AOFF + c][r] += s;
      }
    }
  }
}

template<int P, int AOFF>
__device__ __forceinline__ void z_contract(const unsigned short* __restrict__ x1s,
    const float* __restrict__ gin, const bhalf8 (&bfrag)[4],
    floatx4 (&acc)[8], const int lr, const int lg, const unsigned xsw)
{
  using namespace so3;
  constexpr int n1 = 2*H_L1[P] + 1;
  if constexpr (n1 == 1) {
    chunk_op<P, AOFF, 0, 1>(x1s, gin, bfrag, acc, lr, lg, xsw);
  } else if constexpr (n1 == 3) {
    chunk_op<P, AOFF, 0, 3>(x1s, gin, bfrag, acc, lr, lg, xsw);
  } else if constexpr (n1 == 5) {
    chunk_op<P, AOFF, 0, 4>(x1s, gin, bfrag, acc, lr, lg, xsw);
    chunk_op<P, AOFF, 4, 1>(x1s, gin, bfrag, acc, lr, lg, xsw);
  } else {
    chunk_op<P, AOFF, 0, 4>(x1s, gin, bfrag, acc, lr, lg, xsw);
    chunk_op<P, AOFF, 4, 3>(x1s, gin, bfrag, acc, lr, lg, xsw);
  }
}

// ---------------------------------------------------------------------------
// Per-path interval (one raw barrier each). Order (register-lifetime-safe):
//   stage A for path Q+1 -> gsh[(Q+1)&1]
//   {z-phase + contraction} for path Q (reads gsh[Q&1], x1s, bfrag)
//   prefetch bfrag for path Q+1 (vmcnt survives the barrier)
//   SO3_BAR
// Math and all index patterns verified in r8 (passed, absmax 0.03125).
// ---------------------------------------------------------------------------
template<int LOA, int LOB, int Q>
__device__ __forceinline__ void q_iter(const int tid,
    const unsigned short* __restrict__ x1s, float* __restrict__ gsh,
    const float* __restrict__ x2s, const unsigned short* __restrict__ wT,
    floatx4 (&acc)[8], bhalf8 (&bfrag)[4])
{
  using namespace so3;
  constexpr int QCNT = H_CNT[LOA] + H_CNT[LOB];
  constexpr int GS   = 7*16*8;
  if constexpr (Q >= QCNT) { return; }
  else {
    constexpr int P    = pid_of(LOA, LOB, Q);
    constexpr int AOFF = (Q < H_CNT[LOA]) ? 0 : (2*LOA + 1);

    const int lane = tid & 63, wv = tid >> 6, lr = lane & 15, lg = lane >> 4;
    const unsigned xsw = (unsigned)((lr & 7) << 4);

    if constexpr (Q + 1 < QCNT) {
      stage_a<pid_of(LOA, LOB, Q + 1)>(tid, gsh + ((Q+1)&1)*GS, x2s);
    }

    z_contract<P, AOFF>(x1s, gsh + (Q&1)*GS, bfrag, acc, lr, lg, xsw);

    if constexpr (Q + 1 < QCNT) {
      constexpr int PN = pid_of(LOA, LOB, Q + 1);
      const unsigned short* wp = wT + PN*16384 + (wv*16 + lr)*128 + lg*8;
      #pragma unroll
      for (int ks = 0; ks < 4; ++ks)
        bfrag[ks] = *(const bhalf8*)(wp + ks*32);
    }

    SO3_BAR();
    q_iter<LOA, LOB, Q+1>(tid, x1s, gsh, x2s, wT, acc, bfrag);
  }
}

// ---------------------------------------------------------------------------
// Paired-lo kernel: 512 thr (8 waves x 16 cols), 16 nodes/block.
// LDS: x1s 64KB (bf16, swizzled, staged once) + gsh 7KB + x2s 1KB = 72KB
// -> 2 blocks/CU.
// ---------------------------------------------------------------------------
template<int LOA, int LOB>
__global__ __launch_bounds__(512, 4)
void so3_pair(const float* __restrict__ x1, const float* __restrict__ x2,
              const unsigned short* __restrict__ wT, float* __restrict__ out)
{
  using namespace so3;
  constexpr int NRA = 2*LOA + 1, NRB = 2*LOB + 1;
  constexpr int GS = 7*16*8;
  __shared__ __align__(16) char smem[65536 + 2*GS*4 + 1024];
  unsigned short* x1s = (unsigned short*)smem;          // 65536 B, swizzled
  float* gsh = (float*)(smem + 65536);                  // 7168 B (2 bufs)
  float* x2s = (float*)(smem + 65536 + 2*GS*4);         // 1024 B

  const int tid = threadIdx.x;
  const long n0 = (long)blockIdx.x * MT;
  const int bn = tid >> 5, u4 = tid & 31;

  // --- prologue: stage x1 (f32 -> bf16, swizzled; verified r8) and x2 ---
  {
    const float* xp = x1 + ((size_t)(n0 + bn) * IRR) * CIN + u4*4;
    #pragma unroll
    for (int r = 0; r < 16; ++r) {
      const float4 v = *(const float4*)(xp + r*CIN);
      uint2 o;
      o.x = f2bf(v.x) | (f2bf(v.y) << 16);
      o.y = f2bf(v.z) | (f2bf(v.w) << 16);
      const unsigned byte = ((unsigned)(((r*16 + bn)*128 + u4*4)*2)) ^ ((unsigned)((bn & 7) << 4));
      *(uint2*)((char*)x1s + byte) = o;
    }
  }
  if (tid < 256) x2s[tid] = x2[n0*16 + tid];

  // prefetch weights for path q=0 (vmcnt not drained by SO3_BAR)
  bhalf8 bfrag[4];
  {
    constexpr int P0 = pid_of(LOA, LOB, 0);
    const int lane = tid & 63, wv = tid >> 6, lr = lane & 15, lg = lane >> 4;
    const unsigned short* wp = wT + P0*16384 + (wv*16 + lr)*128 + lg*8;
    #pragma unroll
    for (int ks = 0; ks < 4; ++ks)
      bfrag[ks] = *(const bhalf8*)(wp + ks*32);
  }
  SO3_BAR();                       // x2s/x1s visible
  stage_a<pid_of(LOA, LOB, 0)>(tid, gsh, x2s);
  SO3_BAR();

  floatx4 acc[8];
  #pragma unroll
  for (int i = 0; i < 8; ++i) acc[i] = (floatx4){0.f,0.f,0.f,0.f};

  q_iter<LOA, LOB, 0>(tid, x1s, gsh, x2s, wT, acc, bfrag);

  // --- coalesced epilogue (verified r4/r7/r8 verbatim) ---
  float* epi = (float*)smem;   // 4*16*132*4 = 33792 B, reuses x1s space
  const int lane = tid & 63, wv = tid >> 6, lr = lane & 15, lg = lane >> 4;
  const int v = wv*16 + lr;
  #pragma unroll
  for (int ch = 0; ch < 2; ++ch) {
    if (ch) __syncthreads();           // chunk0 reads done before overwrite
    #pragma unroll
    for (int ii = 0; ii < 4; ++ii) {   // acc index static (rule #20)
      #pragma unroll
      for (int r = 0; r < 4; ++r)
        epi[(ii*16 + lg*4 + r)*132 + v] = acc[ch*4 + ii][r];
    }
    __syncthreads();
    #pragma unroll
    for (int j = 0; j < 4; ++j) {
      const int k   = tid + j*512;     // float4 index within chunk
      const int row = k >> 5, c4 = k & 31;
      const int n   = row >> 2, ii = row & 3;
      const int idx = ch*4 + ii;
      const int gi  = (idx < NRA) ? (LOA*LOA + idx) : (LOB*LOB + idx - NRA);
      const float4 val = *(const float4*)(epi + (ii*16 + n)*132 + c4*4);
      *(float4*)(out + ((n0 + n)*16 + gi)*128 + c4*4) = val;
    }
  }
}

// Prep: w (34,128,128) f32 -> wT[p][v][u] bf16 in d_ws (transposed, 1.06 MiB)
__global__ void prep_wT(const float* __restrict__ w, unsigned short* __restrict__ wT)
{
  const int idx = blockIdx.x*256 + threadIdx.x;
  if (idx >= 34*128*128) return;
  const int p = idx >> 14, rem = idx & 16383, u = rem >> 7, v = rem & 127;
  wT[(p << 14) + (v << 7) + u] = (unsigned short)f2bf(w[idx]);
}

extern "C" void kernel_launch(void* const* d_in, const int* in_sizes, int n_in,
                              void* d_out, int out_size, void* d_ws, size_t ws_size,
                              hipStream_t stream)
{
  (void)in_sizes; (void)n_in; (void)out_size; (void)ws_size;
  const float* x1 = (const float*)d_in[0];   // (16384, 16, 128) f32
  const float* x2 = (const float*)d_in[1];   // (16384, 16)      f32
  const float* w  = (const float*)d_in[2];   // (34, 128, 128)   f32
  float* out = (float*)d_out;

  unsigned short* wT = (unsigned short*)d_ws;
  prep_wT<<<dim3(2176), dim3(256), 0, stream>>>(w, wT);
  // irreps {0, 9..15} and {1..8}: disjoint rows, each written exactly once
  so3_pair<0,3><<<dim3(so3::NNODES / so3::MT), dim3(512), 0, stream>>>(x1, x2, wT, out);
  so3_pair<1,2><<<dim3(so3::NNODES / so3::MT), dim3(512), 0, stream>>>(x1, x2, wT, out);
}

// Round 10
// 308.032 us; speedup vs baseline: 13.8558x; 13.8558x over previous
//
#include <hip/hip_runtime.h>
#include <cstddef>

// ---------------------------------------------------------------------------
// Compile-time generation of real-basis Clebsch-Gordan tensors (e3nn conv.)
// (verified correct in rounds 1-9)
// ---------------------------------------------------------------------------
namespace so3 {

constexpr int IRR  = 16;
constexpr int CIN  = 128;
constexpr int COUT = 128;
constexpr int NP   = 34;
constexpr int NNODES = 16384;
constexpr int MT   = 16;

constexpr int H_L1[NP] = {0,1,2,3, 0,1,1,1,2,2,2,3,3, 0,1,1,1,2,2,2,2,3,3,3, 0,1,1,2,2,2,3,3,3,3};
constexpr int H_L2[NP] = {0,1,2,3, 1,0,1,2,1,2,3,2,3, 2,1,2,3,0,1,2,3,1,2,3, 3,2,3,1,2,3,0,1,2,3};
constexpr int H_LO[NP] = {0,0,0,0, 1,1,1,1,1,1,1,1,1, 2,2,2,2,2,2,2,2,2,2,2, 3,3,3,3,3,3,3,3,3,3};
constexpr int H_START[4] = {0,4,13,24};
constexpr int H_CNT[4]   = {4,9,11,10};

constexpr double cfac(int n){ double r=1.0; for(int i=2;i<=n;++i) r *= (double)i; return r; }
constexpr double csqrt_(double x){
  if(x <= 0.0) return 0.0;
  double r = x < 1.0 ? 1.0 : x;
  for(int i=0;i<60;++i) r = 0.5*(r + x/r);
  return r;
}
constexpr double m1pow(int k){ return (k & 1) ? -1.0 : 1.0; }

struct CD { double re, im; };
constexpr CD cmul(CD a, CD b){ return CD{a.re*b.re - a.im*b.im, a.re*b.im + a.im*b.re}; }

struct CGDense { double v[7][7][7]; };
constexpr CGDense su2_cg(int j1,int j2,int j3){
  CGDense C{};
  for(int m1=-j1;m1<=j1;++m1){
    for(int m2=-j2;m2<=j2;++m2){
      int m3 = m1+m2;
      if(m3 < -j3 || m3 > j3) continue;
      double pref = csqrt_((2*j3+1) * cfac(j3+j1-j2)*cfac(j3-j1+j2)*cfac(j1+j2-j3)/cfac(j1+j2+j3+1));
      pref *= csqrt_(cfac(j3+m3)*cfac(j3-m3)*cfac(j1-m1)*cfac(j1+m1)*cfac(j2-m2)*cfac(j2+m2));
      double s = 0.0;
      for(int k=0;k<=j1+j2;++k){
        int d0=k, d1=j1+j2-j3-k, d2=j1-m1-k, d3=j2+m2-k, d4=j3-j2+m1+k, d5=j3-j1-m2+k;
        if(d0<0||d1<0||d2<0||d3<0||d4<0||d5<0) continue;
        s += m1pow(k)/(cfac(d0)*cfac(d1)*cfac(d2)*cfac(d3)*cfac(d4)*cfac(d5));
      }
      C.v[m1+j1][m2+j2][m3+j3] = pref*s;
    }
  }
  return C;
}

struct QMat { CD v[7][7]; };
constexpr QMat qmat(int l){
  QMat q{};
  const double r2 = 1.0/csqrt_(2.0);
  for(int m=-l;m<0;++m){
    q.v[l+m][l-m] = CD{r2, 0.0};
    q.v[l+m][l+m] = CD{0.0, -r2};
  }
  q.v[l][l] = CD{1.0, 0.0};
  for(int m=1;m<=l;++m){
    double sgn = m1pow(m);
    q.v[l+m][l+m] = CD{sgn*r2, 0.0};
    q.v[l+m][l-m] = CD{0.0, sgn*r2};
  }
  CD ph = CD{1.0, 0.0};
  int lm = l & 3;
  if(lm==1) ph = CD{0.0,-1.0};
  else if(lm==2) ph = CD{-1.0,0.0};
  else if(lm==3) ph = CD{0.0, 1.0};
  for(int i=0;i<2*l+1;++i)
    for(int j=0;j<2*l+1;++j)
      q.v[i][j] = cmul(q.v[i][j], ph);
  return q;
}

struct RealCG { double v[7][7][7]; };
constexpr RealCG real_cg(int l1,int l2,int l3){
  RealCG W{};
  const CGDense C = su2_cg(l1,l2,l3);
  const QMat q1 = qmat(l1), q2 = qmat(l2), q3 = qmat(l3);
  for(int i=0;i<2*l1+1;++i){
    int alist[2] = {i, 2*l1-i};
    int na = (alist[1]==alist[0]) ? 1 : 2;
    for(int j=0;j<2*l2+1;++j){
      int blist[2] = {j, 2*l2-j};
      int nb = (blist[1]==blist[0]) ? 1 : 2;
      for(int k=0;k<2*l3+1;++k){
        int clist[2] = {k, 2*l3-k};
        int nc = (clist[1]==clist[0]) ? 1 : 2;
        double re = 0.0;
        for(int ai=0;ai<na;++ai) for(int bi=0;bi<nb;++bi) for(int ci=0;ci<nc;++ci){
          int a=alist[ai], b=blist[bi], c=clist[ci];
          double cc = C.v[a][b][c];
          if(cc == 0.0) continue;
          CD t = cmul(cmul(q1.v[a][i], q2.v[b][j]), q3.v[c][k]);
          re += t.re * cc;
        }
        W.v[i][j][k] = re;
      }
    }
  }
  return W;
}

#define DECL_CG(n,a,b,c) constexpr RealCG CGP##n = real_cg(a,b,c);
DECL_CG(0,0,0,0)  DECL_CG(1,1,1,0)  DECL_CG(2,2,2,0)  DECL_CG(3,3,3,0)
DECL_CG(4,0,1,1)  DECL_CG(5,1,0,1)  DECL_CG(6,1,1,1)  DECL_CG(7,1,2,1)
DECL_CG(8,2,1,1)  DECL_CG(9,2,2,1)  DECL_CG(10,2,3,1) DECL_CG(11,3,2,1)
DECL_CG(12,3,3,1) DECL_CG(13,0,2,2) DECL_CG(14,1,1,2) DECL_CG(15,1,2,2)
DECL_CG(16,1,3,2) DECL_CG(17,2,0,2) DECL_CG(18,2,1,2) DECL_CG(19,2,2,2)
DECL_CG(20,2,3,2) DECL_CG(21,3,1,2) DECL_CG(22,3,2,2) DECL_CG(23,3,3,2)
DECL_CG(24,0,3,3) DECL_CG(25,1,2,3) DECL_CG(26,1,3,3) DECL_CG(27,2,1,3)
DECL_CG(28,2,2,3) DECL_CG(29,2,3,3) DECL_CG(30,3,0,3) DECL_CG(31,3,1,3)
DECL_CG(32,3,2,3) DECL_CG(33,3,3,3)
#undef DECL_CG

struct CGTable { float v[NP][7][7][7]; };
constexpr CGTable pack_cg(){
  const RealCG arr[NP] = {CGP0,CGP1,CGP2,CGP3,CGP4,CGP5,CGP6,CGP7,CGP8,CGP9,
                          CGP10,CGP11,CGP12,CGP13,CGP14,CGP15,CGP16,CGP17,CGP18,CGP19,
                          CGP20,CGP21,CGP22,CGP23,CGP24,CGP25,CGP26,CGP27,CGP28,CGP29,
                          CGP30,CGP31,CGP32,CGP33};
  CGTable t{};
  for(int p=0;p<NP;++p)
    for(int i=0;i<7;++i) for(int j=0;j<7;++j) for(int k=0;k<7;++k)
      t.v[p][i][j][k] = (float)arr[p].v[i][j][k];
  return t;
}

constexpr float PATH_SC[4] = {
  (float)(1.0/csqrt_((double)H_CNT[0])), (float)(1.0/csqrt_((double)H_CNT[1])),
  (float)(1.0/csqrt_((double)H_CNT[2])), (float)(1.0/csqrt_((double)H_CNT[3]))
};

} // namespace so3

// Compile-time CG table: referenced ONLY in constant expressions -> every
// coefficient folds to an inline literal; no runtime storage, no loads.
constexpr so3::CGTable CG_HOST = so3::pack_cg();

typedef __attribute__((ext_vector_type(8))) short bhalf8;
typedef __attribute__((ext_vector_type(4))) float floatx4;

__device__ __forceinline__ unsigned f2bf(float f){
  unsigned u = __builtin_bit_cast(unsigned, f);
  return (u + 0x7fffu + ((u>>16)&1u)) >> 16;
}

// Raw barrier: LDS-count + s_barrier, NO vmcnt drain -> global loads stay in
// flight across intervals. All cross-thread traffic is LDS-only.
#define SO3_BAR() do{ __builtin_amdgcn_sched_barrier(0); \
  asm volatile("s_waitcnt lgkmcnt(0)" ::: "memory"); \
  __builtin_amdgcn_s_barrier(); \
  asm volatile("" ::: "memory"); \
  __builtin_amdgcn_sched_barrier(0); }while(0)

// ---------------------------------------------------------------------------
// NEW stage A (this round's single delta): compile-time-folded CG dot.
//   g[c][n][a] = sum_b (CG[a][b][c]*sc) * x2[n, l2^2+b]
// Slot S=(c,a) is handled by the 16-lane group ca==S (n = tid&15). All CG
// coefficients are inline literals (PATH_SC folded, exact zeros elided).
// x2s has stride 17 -> the 16-lane broadcast reads are bank-conflict-free.
// ---------------------------------------------------------------------------
template<int P, int C, int A, int B>
__device__ __forceinline__ float cg_dot(const float* __restrict__ x2r)
{
  using namespace so3;
  constexpr int n2 = 2*H_L2[P] + 1;
  if constexpr (B >= n2) { (void)x2r; return 0.f; }
  else {
    constexpr float w = CG_HOST.v[P][A][B][C] * PATH_SC[H_LO[P]];
    float r = cg_dot<P, C, A, B+1>(x2r);
    if constexpr (w != 0.0f) r += w * x2r[B];
    return r;
  }
}

template<int P, int S, int SEND>
__device__ __forceinline__ void stage_a_slots(const int ca,
    float* __restrict__ gout, const float* __restrict__ x2r, const int n)
{
  using namespace so3;
  if constexpr (S < SEND) {
    constexpr int n1 = 2*H_L1[P] + 1;
    constexpr int c = S / n1, a = S % n1;
    if (ca == S) gout[(c*16 + n)*8 + a] = cg_dot<P, c, a, 0>(x2r);
    stage_a_slots<P, S+1, SEND>(ca, gout, x2r, n);
  }
}

template<int P>
__device__ __forceinline__ void stage_a(const int tid, float* __restrict__ gout,
                                        const float* __restrict__ x2s)
{
  using namespace so3;
  constexpr int n1 = 2*H_L1[P] + 1;
  constexpr int NS = (2*H_LO[P] + 1) * n1;   // <= 49
  const int n  = tid & 15;
  const int ca = tid >> 4;                   // 0..31, uniform per 16-lane group
  const float* x2r = x2s + n*17 + H_L2[P]*H_L2[P];
  stage_a_slots<P, 0, (NS < 32 ? NS : 32)>(ca, gout, x2r, n);
  if constexpr (NS > 32)
    stage_a_slots<P, 32, NS>(ca + 32, gout, x2r, n);
}

// ---------------------------------------------------------------------------
// Per-path iterator (r7-benched structure, verbatim except stage_a call):
// one raw barrier per path, double-buffered Tsh/gsh, 8 waves x 16-col tiles,
// xf[7] registers loaded once per l1-group (canonical order is l1-sorted).
// ---------------------------------------------------------------------------
template<int LO, int PP, int AOFF, int NIRR>
__device__ __forceinline__ void path_iter(const int tid, const long n0,
    const float* __restrict__ x1, unsigned short* __restrict__ Tsh,
    float* __restrict__ gsh, const float* __restrict__ x2s,
    const unsigned short* __restrict__ wT,
    floatx4 (&acc)[NIRR], bhalf8 (&bfrag)[4], float4 (&xf)[7])
{
  using namespace so3;
  constexpr int NR  = 2*LO + 1;
  constexpr int CNT = H_CNT[LO];
  constexpr int TS  = 7*16*128;   // shorts per T buffer (fixed max stride)
  constexpr int GS  = 7*16*8;     // floats per g buffer
  if constexpr (PP > CNT) { return; }
  else {
    const int lane = tid & 63, wv = tid >> 6, lr = lane & 15, lg = lane >> 4;
    const int bn = tid >> 5, u4 = tid & 31;

    if constexpr (PP > 0) {        // B-frags (weights) for path PP-1 (L2-hot)
      constexpr int p = H_START[LO] + PP - 1;
      const unsigned short* wp = wT + p*16384 + (wv*16 + lr)*128 + lg*8;
      #pragma unroll
      for (int ks = 0; ks < 4; ++ks)
        bfrag[ks] = *(const bhalf8*)(wp + ks*32);
    }

    if constexpr (PP < CNT) {      // xf group load (once per l1-group)
      constexpr int p  = H_START[LO] + PP;
      constexpr int l1 = H_L1[p];
      constexpr bool newg = (PP == 0) || (H_L1[p - 1] != l1);
      if constexpr (newg) {
        constexpr int n1 = 2*l1 + 1;
        const float* xp = x1 + ((size_t)(n0 + bn)*IRR + l1*l1)*CIN + u4*4;
        #pragma unroll
        for (int a = 0; a < n1; ++a)
          xf[a] = *(const float4*)(xp + a*CIN);
      }
    }

    if constexpr (PP + 1 < CNT) {  // stage A for path PP+1 -> gsh[(PP+1)&1]
      stage_a<H_START[LO] + PP + 1>(tid, gsh + ((PP+1)&1)*GS, x2s);
    }

    if constexpr (PP < CNT) {      // stage B: T = sum_a g*xf -> Tsh[PP&1]
      constexpr int p  = H_START[LO] + PP;
      constexpr int l1 = H_L1[p]; constexpr int n1 = 2*l1 + 1;
      const float* gin = gsh + (PP&1)*GS;
      char* Tbase = (char*)Tsh + (PP&1)*(TS*2);
      #pragma unroll
      for (int c = 0; c < NR; ++c) {
        const float* g8 = gin + (c*16 + bn)*8;
        float garr[8];
        const float4 ga = *(const float4*)(g8);
        garr[0]=ga.x; garr[1]=ga.y; garr[2]=ga.z; garr[3]=ga.w;
        if constexpr (n1 > 4) {
          const float4 gb = *(const float4*)(g8 + 4);
          garr[4]=gb.x; garr[5]=gb.y; garr[6]=gb.z; garr[7]=gb.w;
        }
        float t0=0.f, t1=0.f, t2=0.f, t3=0.f;
        #pragma unroll
        for (int a = 0; a < n1; ++a) {
          const float4 xa = xf[a];
          t0 += garr[a]*xa.x; t1 += garr[a]*xa.y;
          t2 += garr[a]*xa.z; t3 += garr[a]*xa.w;
        }
        uint2 o;
        o.x = f2bf(t0) | (f2bf(t1) << 16);
        o.y = f2bf(t2) | (f2bf(t3) << 16);
        const unsigned byte = ((unsigned)(((c*16 + bn)*128 + u4*4)*2)) ^ ((unsigned)((bn & 7) << 4));
        *(uint2*)(Tbase + byte) = o;
      }
    }

    if constexpr (PP > 0) {        // MFMA for path PP-1
      const char* Tbase = (const char*)Tsh + ((PP-1)&1)*(TS*2);
      const unsigned xsw = (unsigned)((lr & 7) << 4);
      #pragma unroll
      for (int c = 0; c < NR; ++c) {
        #pragma unroll
        for (int ks = 0; ks < 4; ++ks) {
          const unsigned byte = ((unsigned)((c*16 + lr)*256) + (unsigned)(ks*64 + lg*16)) ^ xsw;
          bhalf8 av = *(const bhalf8*)(Tbase + byte);
          acc[AOFF + c] = __builtin_amdgcn_mfma_f32_16x16x32_bf16(
              av, bfrag[ks], acc[AOFF + c], 0, 0, 0);
        }
      }
    }

    SO3_BAR();
    path_iter<LO, PP+1, AOFF, NIRR>(tid, n0, x1, Tsh, gsh, x2s, wT, acc, bfrag, xf);
  }
}

// ---------------------------------------------------------------------------
// Paired-lo kernel (r7-benched shell): lo-groups LOA then LOB.
// 512 thr, LDS ~64KB -> 2 blocks/CU.
// ---------------------------------------------------------------------------
template<int LOA, int LOB>
__global__ __launch_bounds__(512, 4)
void so3_pair(const float* __restrict__ x1, const float* __restrict__ x2,
              const unsigned short* __restrict__ wT, float* __restrict__ out)
{
  using namespace so3;
  constexpr int NRA = 2*LOA + 1, NRB = 2*LOB + 1, NIRR = NRA + NRB;  // = 8
  __shared__ __align__(16) char smem[57344 + 7168 + 1152];
  unsigned short* Tsh = (unsigned short*)smem;            // 57344 B (2 bufs)
  float* gsh = (float*)(smem + 57344);                    // 7168 B (2 bufs)
  float* x2s = (float*)(smem + 57344 + 7168);             // 1088 B (stride 17)

  const int tid = threadIdx.x;
  const long n0 = (long)blockIdx.x * MT;

  if (tid < 256) x2s[(tid >> 4)*17 + (tid & 15)] = x2[n0*16 + tid];
  __syncthreads();

  floatx4 acc[NIRR];
  #pragma unroll
  for (int i = 0; i < NIRR; ++i) acc[i] = (floatx4){0.f,0.f,0.f,0.f};
  bhalf8 bfrag[4];
  float4 xf[7];

  stage_a<H_START[LOA]>(tid, gsh, x2s);
  __syncthreads();
  path_iter<LOA, 0, 0, NIRR>(tid, n0, x1, Tsh, gsh, x2s, wT, acc, bfrag, xf);
  __syncthreads();
  stage_a<H_START[LOB]>(tid, gsh, x2s);
  __syncthreads();
  path_iter<LOB, 0, NRA, NIRR>(tid, n0, x1, Tsh, gsh, x2s, wT, acc, bfrag, xf);
  __syncthreads();

  // Coalesced epilogue (verified r4/r7 verbatim): stage acc via LDS, 512B rows.
  float* epi = (float*)smem;   // 4*16*132*4 = 33792 B, reuses Tsh space
  const int lane = tid & 63, wv = tid >> 6, lr = lane & 15, lg = lane >> 4;
  const int v = wv*16 + lr;
  #pragma unroll
  for (int ch = 0; ch < 2; ++ch) {
    if (ch) __syncthreads();           // chunk0 reads done before overwrite
    #pragma unroll
    for (int ii = 0; ii < 4; ++ii) {   // acc index static (rule #20)
      #pragma unroll
      for (int r = 0; r < 4; ++r)
        epi[(ii*16 + lg*4 + r)*132 + v] = acc[ch*4 + ii][r];
    }
    __syncthreads();
    #pragma unroll
    for (int j = 0; j < 4; ++j) {
      const int k   = tid + j*512;     // float4 index within chunk
      const int row = k >> 5, c4 = k & 31;
      const int n   = row >> 2, ii = row & 3;
      const int idx = ch*4 + ii;
      const int gi  = (idx < NRA) ? (LOA*LOA + idx) : (LOB*LOB + idx - NRA);
      const float4 val = *(const float4*)(epi + (ii*16 + n)*132 + c4*4);
      *(float4*)(out + ((n0 + n)*16 + gi)*128 + c4*4) = val;
    }
  }
}

// Prep: w (34,128,128) f32 -> wT[p][v][u] bf16 in d_ws (transposed, 1.06 MiB)
__global__ void prep_wT(const float* __restrict__ w, unsigned short* __restrict__ wT)
{
  const int idx = blockIdx.x*256 + threadIdx.x;
  if (idx >= 34*128*128) return;
  const int p = idx >> 14, rem = idx & 16383, u = rem >> 7, v = rem & 127;
  wT[(p << 14) + (v << 7) + u] = (unsigned short)f2bf(w[idx]);
}

extern "C" void kernel_launch(void* const* d_in, const int* in_sizes, int n_in,
                              void* d_out, int out_size, void* d_ws, size_t ws_size,
                              hipStream_t stream)
{
  (void)in_sizes; (void)n_in; (void)out_size; (void)ws_size;
  const float* x1 = (const float*)d_in[0];   // (16384, 16, 128) f32
  const float* x2 = (const float*)d_in[1];   // (16384, 16)      f32
  const float* w  = (const float*)d_in[2];   // (34, 128, 128)   f32
  float* out = (float*)d_out;

  unsigned short* wT = (unsigned short*)d_ws;
  prep_wT<<<dim3(2176), dim3(256), 0, stream>>>(w, wT);
  // irreps {0, 9..15} and {1..8}: disjoint rows, each written exactly once
  so3_pair<0,3><<<dim3(so3::NNODES / so3::MT), dim3(512), 0, stream>>>(x1, x2, wT, out);
  so3_pair<1,2><<<dim3(so3::NNODES / so3::MT), dim3(512), 0, stream>>>(x1, x2, wT, out);
}